// Round 13
// baseline (157.481 us; speedup 1.0000x reference)
//
#include <hip/hip_runtime.h>

#define N_TASKS 16
#define LMAX 64
#define TSTRIDE 136  // dwords per task row (A/B-neutral vs 128; kept from R8)

typedef float f32x4 __attribute__((ext_vector_type(4)));

__global__ __launch_bounds__(256) void MultiElementWiseAffine_kernel(
    const float* __restrict__ input,      // [B]
    const int*   __restrict__ task_ids,   // [B]
    const float* __restrict__ offsets,    // [N_TASKS*LMAX]
    const float* __restrict__ disc,       // [N_TASKS*LMAX]
    const int*   __restrict__ lengths,    // [N_TASKS]
    f32x4*       __restrict__ out,        // [B*16] float4 view of [B][64]
    int total4)                           // B*16
{
    // Per-task: [t*136 + 0..63] = masked disc (m), [t*136 + 64..127] = m*offset.
    __shared__ alignas(16) float s_tab[N_TASKS * TSTRIDE];

    for (int i = threadIdx.x; i < N_TASKS * LMAX; i += blockDim.x) {
        int t = i >> 6;          // task
        int k = i & (LMAX - 1);  // threshold index
        float m = (k < lengths[t]) ? disc[i] : 0.0f;
        s_tab[t * TSTRIDE + k]      = m;
        s_tab[t * TSTRIDE + 64 + k] = m * offsets[i];
    }
    __syncthreads();

    const int stride = gridDim.x * blockDim.x;
    int g = blockIdx.x * blockDim.x + threadIdx.x;
    if (g >= total4) return;

    // 2-stage pipeline: next iteration's row data prefetched -> table ds_reads
    // issue at loop top (single LDS hop per iteration). In-loop gathers are
    // PROVEN faster than LDS row-staging (R7/R9/R11 all ~ +15us).
    int   t_cur = task_ids[g >> 4];
    float x_cur = input[g >> 4];

    for (; g < total4; g += stride) {
        int gn      = g + stride;
        int rown    = (gn < total4 ? gn : g) >> 4;
        int t_nxt   = task_ids[rown];
        float x_nxt = input[rown];

        int k4 = g & 15;
        const float* base = &s_tab[t_cur * TSTRIDE + (k4 << 2)];
        f32x4 mv = *(const f32x4*)(base);       // ds_read_b128
        f32x4 pv = *(const f32x4*)(base + 64);  // ds_read_b128 offset:256
        f32x4 r;
        r.x = fmaf(mv.x, x_cur, pv.x);
        r.y = fmaf(mv.y, x_cur, pv.y);
        r.z = fmaf(mv.z, x_cur, pv.z);
        r.w = fmaf(mv.w, x_cur, pv.w);
        // Lane-dense 1KB/wave, grid-stride walk, nt (all A/B-proven).
        __builtin_nontemporal_store(r, &out[g]);

        t_cur = t_nxt;
        x_cur = x_nxt;
    }
}

extern "C" void kernel_launch(void* const* d_in, const int* in_sizes, int n_in,
                              void* d_out, int out_size, void* d_ws, size_t ws_size,
                              hipStream_t stream) {
    const float* input    = (const float*)d_in[0];
    const int*   task_ids = (const int*)d_in[1];
    const float* offsets  = (const float*)d_in[2];
    const float* disc     = (const float*)d_in[3];
    const int*   lengths  = (const int*)d_in[4];
    f32x4*       out      = (f32x4*)d_out;

    int total4 = out_size / 4;           // B * 16
    int block  = 256;
    // ONLY change vs R12: grid 512 -> 256 (1 block/CU, like the 7 TB/s fill).
    // Sweep: 2048 -> 52.5us, 512 -> 48.6us, 256 -> ?
    int grid   = 256;

    MultiElementWiseAffine_kernel<<<grid, block, 0, stream>>>(
        input, task_ids, offsets, disc, lengths, out, total4);
}

// Round 14
// 54.587 us; speedup vs baseline: 2.8850x; 2.8850x over previous
//
#include <hip/hip_runtime.h>

#define N_TASKS 16
#define LMAX 64
#define TSTRIDE 136
#define BLOCK 256
#define GRID 512            // R12-proven stream concurrency (2 blocks/CU)
#define ITERS 128           // total4 / (GRID*BLOCK) for B=1M
#define ROWS_PER_BLOCK (ITERS * 16)   // 2048 rows, 16 KB LDS

typedef float f32x4 __attribute__((ext_vector_type(4)));
typedef float f32x2 __attribute__((ext_vector_type(2)));

// Hot kernel (requires total4 == GRID*BLOCK*ITERS): R12's exact store walk
// (grid-stride, lane-dense 1KB/wave, nt) but with ALL global loads hoisted to
// a prologue LDS staging burst. Steady-state loop touches only LDS + stores:
// vmcnt counts ONLY stores -> no s_waitcnt vmcnt in the loop -> each wave
// pipelines stores to queue depth instead of ~1 in flight (the vmcnt counter
// is shared in-order by loads+stores; any in-loop load-use wait drains all
// older stores).
__global__ __launch_bounds__(BLOCK) void MEWA_exact_kernel(
    const float* __restrict__ input,      // [B]
    const int*   __restrict__ task_ids,   // [B]
    const float* __restrict__ offsets,    // [N_TASKS*LMAX]
    const float* __restrict__ disc,       // [N_TASKS*LMAX]
    const int*   __restrict__ lengths,    // [N_TASKS]
    f32x4*       __restrict__ out)        // [B*16]
{
    __shared__ alignas(16) float s_tab[N_TASKS * TSTRIDE];
    __shared__ alignas(8)  f32x2 s_row[ROWS_PER_BLOCK + 16];  // +16 pipeline pad

    const int tid          = threadIdx.x;
    const int chunk_stride = GRID * 16;        // rows between iterations
    const int row0         = blockIdx.x * 16;

    for (int i = tid; i < N_TASKS * LMAX; i += BLOCK) {
        int t = i >> 6, k = i & (LMAX - 1);
        float m = (k < lengths[t]) ? disc[i] : 0.0f;
        s_tab[t * TSTRIDE + k]      = m;
        s_tab[t * TSTRIDE + 64 + k] = m * offsets[i];
    }
    // Prologue: stage this block's 2048 rows ({x, task}) into LDS.
    for (int i = tid; i < ROWS_PER_BLOCK + 16; i += BLOCK) {
        f32x2 v; v.x = 0.0f; v.y = __int_as_float(0);
        if (i < ROWS_PER_BLOCK) {
            int r = row0 + (i & 15) + (i >> 4) * chunk_stride;
            v.x = input[r];
            v.y = __int_as_float(task_ids[r]);
        }
        s_row[i] = v;
    }
    __syncthreads();

    const int  k4     = tid & 15;
    const int  lg     = tid >> 4;              // row within chunk
    const long stride = (long)GRID * BLOCK;
    const long gbase  = (long)blockIdx.x * BLOCK + tid;

    f32x2 rv_cur = s_row[lg];                  // prime: iteration 0's row data

    for (int it = 0; it < ITERS; ++it) {
        f32x2 rv_nxt = s_row[(it + 1) * 16 + lg];   // row read for it+1 (no dep)
        float x  = rv_cur.x;
        int   t  = __float_as_int(rv_cur.y);
        const float* base = &s_tab[t * TSTRIDE + (k4 << 2)];
        f32x4 mv = *(const f32x4*)(base);           // ds_read_b128
        f32x4 pv = *(const f32x4*)(base + 64);      // ds_read_b128 offset:256
        f32x4 r;
        r.x = fmaf(mv.x, x, pv.x);
        r.y = fmaf(mv.y, x, pv.y);
        r.z = fmaf(mv.z, x, pv.z);
        r.w = fmaf(mv.w, x, pv.w);
        __builtin_nontemporal_store(r, &out[gbase + it * stride]);  // dense 1KB/wave
        rv_cur = rv_nxt;
    }
}

// Fallback (any size): R12 champion verbatim (in-loop gathers, nt, grid 512).
__global__ __launch_bounds__(BLOCK) void MEWA_generic_kernel(
    const float* __restrict__ input, const int* __restrict__ task_ids,
    const float* __restrict__ offsets, const float* __restrict__ disc,
    const int* __restrict__ lengths, f32x4* __restrict__ out, int total4)
{
    __shared__ alignas(16) float s_tab[N_TASKS * TSTRIDE];
    for (int i = threadIdx.x; i < N_TASKS * LMAX; i += BLOCK) {
        int t = i >> 6, k = i & (LMAX - 1);
        float m = (k < lengths[t]) ? disc[i] : 0.0f;
        s_tab[t * TSTRIDE + k]      = m;
        s_tab[t * TSTRIDE + 64 + k] = m * offsets[i];
    }
    __syncthreads();
    const int stride = gridDim.x * blockDim.x;
    int g = blockIdx.x * blockDim.x + threadIdx.x;
    if (g >= total4) return;
    int   t_cur = task_ids[g >> 4];
    float x_cur = input[g >> 4];
    for (; g < total4; g += stride) {
        int gn = g + stride;
        int rown = (gn < total4 ? gn : g) >> 4;
        int t_nxt = task_ids[rown];
        float x_nxt = input[rown];
        int k4 = g & 15;
        const float* base = &s_tab[t_cur * TSTRIDE + (k4 << 2)];
        f32x4 mv = *(const f32x4*)(base);
        f32x4 pv = *(const f32x4*)(base + 64);
        f32x4 r;
        r.x = fmaf(mv.x, x_cur, pv.x);
        r.y = fmaf(mv.y, x_cur, pv.y);
        r.z = fmaf(mv.z, x_cur, pv.z);
        r.w = fmaf(mv.w, x_cur, pv.w);
        __builtin_nontemporal_store(r, &out[g]);
        t_cur = t_nxt;
        x_cur = x_nxt;
    }
}

extern "C" void kernel_launch(void* const* d_in, const int* in_sizes, int n_in,
                              void* d_out, int out_size, void* d_ws, size_t ws_size,
                              hipStream_t stream) {
    const float* input    = (const float*)d_in[0];
    const int*   task_ids = (const int*)d_in[1];
    const float* offsets  = (const float*)d_in[2];
    const float* disc     = (const float*)d_in[3];
    const int*   lengths  = (const int*)d_in[4];
    f32x4*       out      = (f32x4*)d_out;

    int total4 = out_size / 4;                 // B * 16
    if (total4 == GRID * BLOCK * ITERS) {
        MEWA_exact_kernel<<<GRID, BLOCK, 0, stream>>>(
            input, task_ids, offsets, disc, lengths, out);
    } else {
        int g2 = (total4 + BLOCK - 1) / BLOCK;
        if (g2 > 512) g2 = 512;
        MEWA_generic_kernel<<<g2, BLOCK, 0, stream>>>(
            input, task_ids, offsets, disc, lengths, out, total4);
    }
}

// Round 15
// 48.751 us; speedup vs baseline: 3.2303x; 1.1197x over previous
//
#include <hip/hip_runtime.h>

#define N_TASKS 16
#define LMAX 64
#define TSTRIDE 136  // dwords per task row (A/B-neutral vs 128; kept)

typedef float f32x4 __attribute__((ext_vector_type(4)));

__global__ __launch_bounds__(256) void MultiElementWiseAffine_kernel(
    const float* __restrict__ input,      // [B]
    const int*   __restrict__ task_ids,   // [B]
    const float* __restrict__ offsets,    // [N_TASKS*LMAX]
    const float* __restrict__ disc,       // [N_TASKS*LMAX]
    const int*   __restrict__ lengths,    // [N_TASKS]
    f32x4*       __restrict__ out,        // [B*16] float4 view of [B][64]
    int total4)                           // B*16
{
    // Per-task: [t*136 + 0..63] = masked disc (m), [t*136 + 64..127] = m*offset.
    __shared__ alignas(16) float s_tab[N_TASKS * TSTRIDE];

    for (int i = threadIdx.x; i < N_TASKS * LMAX; i += blockDim.x) {
        int t = i >> 6;          // task
        int k = i & (LMAX - 1);  // threshold index
        float m = (k < lengths[t]) ? disc[i] : 0.0f;
        s_tab[t * TSTRIDE + k]      = m;
        s_tab[t * TSTRIDE + 64 + k] = m * offsets[i];
    }
    __syncthreads();

    const int stride = gridDim.x * blockDim.x;
    const int last   = total4 - 1;
    int g = blockIdx.x * blockDim.x + threadIdx.x;
    if (g >= total4) return;

    // Depth-2 pipeline (ONLY change vs R12's depth-1): iteration i consumes
    // row data loaded at i-2. The s_waitcnt before that use retires only
    // stores <= S_{i-3}, keeping TWO nt stores in flight per wave instead of
    // one (vmcnt is a single in-order counter shared by loads AND stores).
    int g1 = g + stride; g1 = (g1 <= last ? g1 : g);
    int   t0 = task_ids[g >> 4],  t1 = task_ids[g1 >> 4];
    float x0 = input[g >> 4],     x1 = input[g1 >> 4];

    for (; g < total4; g += stride) {
        int g2 = g + 2 * stride; g2 = (g2 <= last ? g2 : last);
        int   t2 = task_ids[g2 >> 4];          // for iteration i+2
        float x2 = input[g2 >> 4];

        int k4 = g & 15;
        const float* base = &s_tab[t0 * TSTRIDE + (k4 << 2)];
        f32x4 mv = *(const f32x4*)(base);       // ds_read_b128
        f32x4 pv = *(const f32x4*)(base + 64);  // ds_read_b128 offset:256
        f32x4 r;
        r.x = fmaf(mv.x, x0, pv.x);
        r.y = fmaf(mv.y, x0, pv.y);
        r.z = fmaf(mv.z, x0, pv.z);
        r.w = fmaf(mv.w, x0, pv.w);
        // Lane-dense 1KB/wave, grid-stride walk, nt (all A/B-proven).
        __builtin_nontemporal_store(r, &out[g]);

        t0 = t1; x0 = x1;
        t1 = t2; x1 = x2;
    }
}

extern "C" void kernel_launch(void* const* d_in, const int* in_sizes, int n_in,
                              void* d_out, int out_size, void* d_ws, size_t ws_size,
                              hipStream_t stream) {
    const float* input    = (const float*)d_in[0];
    const int*   task_ids = (const int*)d_in[1];
    const float* offsets  = (const float*)d_in[2];
    const float* disc     = (const float*)d_in[3];
    const int*   lengths  = (const int*)d_in[4];
    f32x4*       out      = (f32x4*)d_out;

    int total4 = out_size / 4;           // B * 16
    int block  = 256;
    int grid   = 512;                    // R12-proven sweet spot (2 blocks/CU)

    MultiElementWiseAffine_kernel<<<grid, block, 0, stream>>>(
        input, task_ids, offsets, disc, lengths, out, total4);
}